// Round 1
// baseline (304.332 us; speedup 1.0000x reference)
//
#include <hip/hip_runtime.h>
#include <hip/hip_bf16.h>

#define BB 8
#define NN 2048
#define DD 128

typedef __attribute__((ext_vector_type(8))) __bf16 bf16x8;
typedef __attribute__((ext_vector_type(4))) float f32x4;
typedef __attribute__((ext_vector_type(4))) int   i32x4;

static __device__ __forceinline__ unsigned short f2bf(float f) {
    union { float f; unsigned u; } v; v.f = f;
    unsigned r = (v.u + 0x7FFFu + ((v.u >> 16) & 1u)) >> 16;
    return (unsigned short)r;
}
static __device__ __forceinline__ float bf2f(unsigned short b) {
    union { unsigned u; float f; } v; v.u = ((unsigned)b) << 16;
    return v.f;
}

// ---------------------------------------------------------------------------
// kernPW (once per call).
// Blocks [0,4096): pack Ptilde[i][j] = punct[i][j] & mask_j into bits
//   (64 words per row), compute scale[i] and pdm[i]. One wave per row.
// Blocks [4096,5136): f32 -> bf16 conversion of node (-> xb), w_self (-> wsb),
//   w_punct (-> wpb). Same f2bf rounding as the old per-block staging, so the
//   numeric path is bit-identical.
// ---------------------------------------------------------------------------
__global__ __launch_bounds__(256) void kernPW(
    const int* __restrict__ punct, const int* __restrict__ mask,
    const float* __restrict__ node, const float* __restrict__ w_self,
    const float* __restrict__ w_punct,
    unsigned* __restrict__ pk, float* __restrict__ scale_g, float* __restrict__ pdm_g,
    unsigned short* __restrict__ xb, unsigned short* __restrict__ wsb,
    unsigned short* __restrict__ wpb)
{
    const int t = threadIdx.x;
    const int bid = blockIdx.x;

    if (bid < 4096) {
        const int wave = t >> 6, lane = t & 63;
        const int row_g = bid * 4 + wave;               // 0..16383
        const int b = row_g >> 11;
        const int i = row_g & (NN - 1);

        const int* prow = punct + (size_t)row_g * NN;
        const int* mrow = mask + (size_t)b * NN;

        unsigned pk0 = 0, pk1 = 0;
        int acc = 0;
        #pragma unroll 4
        for (int w = 0; w < 32; ++w) {
            const int col = w * 64 + lane;
            const int p = prow[col];
            const int m = mrow[col];
            const int pred = (p & m) & 1;
            unsigned long long bal = __ballot(pred);
            if (lane == w) { pk0 = (unsigned)bal; pk1 = (unsigned)(bal >> 32); }
            acc += pred + ((col == i ? pred : 0) << 16);
        }
        #pragma unroll
        for (int o = 32; o > 0; o >>= 1) acc += __shfl_xor(acc, o, 64);

        if (lane < 32) {
            uint2 w2; w2.x = pk0; w2.y = pk1;
            *(uint2*)(pk + (size_t)row_g * 64 + 2 * lane) = w2;
        }
        if (lane == 0) {
            const int nall = acc & 0xFFFF;
            const int pdm  = acc >> 16;
            const int mi   = mrow[i];
            const int nbr  = nall - pdm;
            scale_g[row_g] = mi ? 1.f / (float)(nbr < 1 ? 1 : nbr) : 0.f;
            pdm_g[row_g]   = (float)pdm;
        }
        return;
    }

    // conversion blocks
    const int cb = bid - 4096;
    const float* src; unsigned short* dst; size_t base;
    if (cb < 1024)      { src = node;    dst = xb;  base = (size_t)cb * 2048; }
    else if (cb < 1032) { src = w_self;  dst = wsb; base = (size_t)(cb - 1024) * 2048; }
    else                { src = w_punct; dst = wpb; base = (size_t)(cb - 1032) * 2048; }
    const size_t i0 = base + (size_t)t * 8;
    f32x4 a = *(const f32x4*)(src + i0);
    f32x4 c = *(const f32x4*)(src + i0 + 4);
    unsigned q0 = f2bf(a.x) | ((unsigned)f2bf(a.y) << 16);
    unsigned q1 = f2bf(a.z) | ((unsigned)f2bf(a.w) << 16);
    unsigned q2 = f2bf(c.x) | ((unsigned)f2bf(c.y) << 16);
    unsigned q3 = f2bf(c.z) | ((unsigned)f2bf(c.w) << 16);
    i32x4 pw = {(int)q0, (int)q1, (int)q2, (int)q3};
    *(i32x4*)(dst + i0) = pw;
}

// ---------------------------------------------------------------------------
// kernB v3: 32-row tiles, grid 512 (2 blocks/CU). A/B MFMA fragments loaded
// DIRECTLY from L2-resident global bf16 (xb / wsb / wpb) — no LDS operand
// staging, no per-block f32->bf16 conversion, only 2 barriers (dw + yT
// transpose). dw computed from f32 x (8-lane groups) exactly as before.
// ---------------------------------------------------------------------------
__global__ __launch_bounds__(256) void kernB(
    const unsigned short* __restrict__ xb,   // [B*N][D] bf16
    const float* __restrict__ xf,            // [B*N][D] f32 (for dw)
    const unsigned short* __restrict__ wsb,  // [D][D] bf16 (w_self)
    const unsigned short* __restrict__ wpb,  // [D][D] bf16 (w_punct)
    const float* __restrict__ w_nw, const float* __restrict__ b_nw,
    const float* __restrict__ b_self,
    float* __restrict__ si_out,
    unsigned short* __restrict__ yne_out,    // [B*N][D] bf16
    unsigned short* __restrict__ yT_out,     // [B][D][N] bf16
    float* __restrict__ aw_out)              // + step*N already applied
{
    __shared__ float dw_l[32];
    __shared__ unsigned short ytl[128 * 40]; // [e][32 rows + pad 8]

    const int t  = threadIdx.x;
    const int n0 = blockIdx.x * 32;
    const int b  = n0 >> 11;
    const int nb = n0 & (NN - 1);
    const int wave = t >> 6, lane = t & 63;
    const int quad = lane >> 4, l16 = lane & 15;

    // ---- dw = sigmoid(x . w_nw + b_nw), one row per 8-lane group ----
    {
        const int row = wave * 8 + (lane >> 3);
        const int seg = (lane & 7) * 16;
        const float* xr = xf + (size_t)(n0 + row) * DD + seg;
        const float* wr = w_nw + seg;
        f32x4 a0 = *(const f32x4*)xr,       a1 = *(const f32x4*)(xr + 4);
        f32x4 a2 = *(const f32x4*)(xr + 8), a3 = *(const f32x4*)(xr + 12);
        f32x4 w0 = *(const f32x4*)wr,       w1 = *(const f32x4*)(wr + 4);
        f32x4 w2 = *(const f32x4*)(wr + 8), w3 = *(const f32x4*)(wr + 12);
        float s = a0.x*w0.x + a0.y*w0.y + a0.z*w0.z + a0.w*w0.w
                + a1.x*w1.x + a1.y*w1.y + a1.z*w1.z + a1.w*w1.w
                + a2.x*w2.x + a2.y*w2.y + a2.z*w2.z + a2.w*w2.w
                + a3.x*w3.x + a3.y*w3.y + a3.z*w3.z + a3.w*w3.w;
        s += __shfl_xor(s, 1, 64);
        s += __shfl_xor(s, 2, 64);
        s += __shfl_xor(s, 4, 64);
        if ((lane & 7) == 0) {
            float dv = 1.f / (1.f + __expf(-(s + b_nw[0])));
            dw_l[row] = dv;
            aw_out[(size_t)b * 2 * NN + nb + row] = dv;
        }
    }

    // ---- GEMMs: si = x@Ws^T, infop = x@Wp^T (32 rows x 128 e per block) ----
    f32x4 accs[2][2] = {}, accp[2][2] = {};
    const unsigned short* xrow = xb + (size_t)n0 * DD;
    #pragma unroll
    for (int kk = 0; kk < 4; ++kk) {
        const int k0 = kk * 32 + quad * 8;
        bf16x8 af[2], bs[2], bp[2];
        #pragma unroll
        for (int mt = 0; mt < 2; ++mt)
            af[mt] = *(const bf16x8*)(xrow + (size_t)(mt * 16 + l16) * DD + k0);
        #pragma unroll
        for (int nt = 0; nt < 2; ++nt) {
            const int e = wave * 32 + nt * 16 + l16;
            bs[nt] = *(const bf16x8*)(wsb + (size_t)e * DD + k0);
            bp[nt] = *(const bf16x8*)(wpb + (size_t)e * DD + k0);
        }
        #pragma unroll
        for (int mt = 0; mt < 2; ++mt)
            #pragma unroll
            for (int nt = 0; nt < 2; ++nt) {
                accs[mt][nt] = __builtin_amdgcn_mfma_f32_16x16x32_bf16(af[mt], bs[nt], accs[mt][nt], 0, 0, 0);
                accp[mt][nt] = __builtin_amdgcn_mfma_f32_16x16x32_bf16(af[mt], bp[nt], accp[mt][nt], 0, 0, 0);
            }
    }

    __syncthreads();   // dw_l ready
    #pragma unroll
    for (int mt = 0; mt < 2; ++mt) {
        #pragma unroll
        for (int nt = 0; nt < 2; ++nt) {
            const int e = wave * 32 + nt * 16 + l16;
            const float bsv = b_self[e];
            #pragma unroll
            for (int r = 0; r < 4; ++r) {
                const int nl = mt * 16 + quad * 4 + r;
                const size_t idx = (size_t)(n0 + nl) * DD + e;
                si_out[idx] = accs[mt][nt][r] + bsv;
                const float yv = dw_l[nl] * accp[mt][nt][r];
                const unsigned short ub = f2bf(yv);
                yne_out[idx] = ub;
                ytl[e * 40 + nl] = ub;
            }
        }
    }
    __syncthreads();
    {
        const int e = t >> 1, half = t & 1;
        const i32x4* src = (const i32x4*)&ytl[e * 40 + half * 16];
        i32x4 v0 = src[0], v1 = src[1];
        i32x4* dst = (i32x4*)(yT_out + (size_t)(b * DD + e) * NN + nb + half * 16);
        dst[0] = v0; dst[1] = v1;
    }
}

// ---------------------------------------------------------------------------
// kernC v4: agg = Ptilde @ yhat. 32-row tiles, grid 512 (2 blocks/CU),
// XCD-aware batch mapping (b = blockIdx & 7 -> all 64 blocks of batch b on
// XCD b, so yT[b] (512 KB) is L2-resident). Zero barriers in the K-loop.
// Epilogue: x = relu(si + scale*(acc - pdm*yhat_i)); also emits x as bf16
// so the next kernB needs no conversion.
// ---------------------------------------------------------------------------
__global__ __launch_bounds__(256) void kernC(
    const unsigned* __restrict__ pk,        // [B*N][64] packed bits
    const float* __restrict__ scale_g, const float* __restrict__ pdm_g,
    const unsigned short* __restrict__ yT,  // [B][D][N] bf16
    const float* __restrict__ si,           // [B*N][D]
    const unsigned short* __restrict__ yne, // [B*N][D] bf16
    float* __restrict__ x_out,              // [B*N][D]
    unsigned short* __restrict__ xb_out)    // [B*N][D] bf16
{
    __shared__ unsigned pPk[32 * 68];       // 32 rows x 64 words, pad 68
    __shared__ float scale_l[32];
    __shared__ float pdm_l[32];

    const int t  = threadIdx.x;
    const int b  = blockIdx.x & 7;          // XCD swizzle: batch b -> XCD b
    const int i0 = (blockIdx.x >> 3) * 32;
    const size_t rg0 = (size_t)b * NN + i0;

    #pragma unroll
    for (int r = 0; r < 2; ++r) {
        const int u   = r * 256 + t;
        const int row = u >> 4;
        const int wq  = (u & 15) * 4;
        i32x4 v = *(const i32x4*)(pk + (rg0 + row) * 64 + wq);
        *(i32x4*)&pPk[row * 68 + wq] = v;
    }
    if (t < 32) {
        scale_l[t] = scale_g[rg0 + t];
        pdm_l[t]   = pdm_g[rg0 + t];
    }
    __syncthreads();

    const int wn = t >> 6, lane = t & 63;
    const int quad = lane >> 4, l16 = lane & 15;
    const unsigned short* yTb = yT + (size_t)b * DD * NN;

    f32x4 acc[2][2] = {};

    #pragma unroll 4
    for (int kk = 0; kk < 64; ++kk) {
        bf16x8 bfr[2];
        #pragma unroll
        for (int nt = 0; nt < 2; ++nt) {
            const int e = wn * 32 + nt * 16 + l16;
            bfr[nt] = *(const bf16x8*)(yTb + (size_t)e * NN + kk * 32 + quad * 8);
        }
        bf16x8 af[2];
        #pragma unroll
        for (int mt = 0; mt < 2; ++mt) {
            const unsigned w = pPk[(mt * 16 + l16) * 68 + kk];
            const unsigned by = (w >> (quad * 8)) & 0xFFu;
            i32x4 ex;
            ex.x = ((by &   1u) ? 0x3F80 : 0) | ((by &   2u) ? 0x3F800000 : 0);
            ex.y = ((by &   4u) ? 0x3F80 : 0) | ((by &   8u) ? 0x3F800000 : 0);
            ex.z = ((by &  16u) ? 0x3F80 : 0) | ((by &  32u) ? 0x3F800000 : 0);
            ex.w = ((by &  64u) ? 0x3F80 : 0) | ((by & 128u) ? 0x3F800000 : 0);
            union { i32x4 i; bf16x8 h; } cv; cv.i = ex;
            af[mt] = cv.h;
        }
        #pragma unroll
        for (int mt = 0; mt < 2; ++mt)
            #pragma unroll
            for (int nt = 0; nt < 2; ++nt)
                acc[mt][nt] = __builtin_amdgcn_mfma_f32_16x16x32_bf16(af[mt], bfr[nt], acc[mt][nt], 0, 0, 0);
    }

    #pragma unroll
    for (int mt = 0; mt < 2; ++mt) {
        #pragma unroll
        for (int nt = 0; nt < 2; ++nt) {
            const int e = wn * 32 + nt * 16 + l16;
            #pragma unroll
            for (int r = 0; r < 4; ++r) {
                const int row = mt * 16 + quad * 4 + r;
                const size_t idx = (rg0 + row) * DD + e;
                const float yv = bf2f(yne[idx]);
                float v = si[idx] + scale_l[row] * (acc[mt][nt][r] - pdm_l[row] * yv);
                v = fmaxf(v, 0.f);
                x_out[idx]  = v;
                xb_out[idx] = f2bf(v);
            }
        }
    }
}

extern "C" void kernel_launch(void* const* d_in, const int* in_sizes, int n_in,
                              void* d_out, int out_size, void* d_ws, size_t ws_size,
                              hipStream_t stream) {
    const float* node   = (const float*)d_in[0];
    const int*   mask   = (const int*)  d_in[1];
    const int*   punct  = (const int*)  d_in[2];
    const float* w_nw   = (const float*)d_in[3];
    const float* b_nw   = (const float*)d_in[4];
    const float* w_self = (const float*)d_in[5];
    const float* b_self = (const float*)d_in[6];
    const float* w_punct= (const float*)d_in[7];

    float* xout = (float*)d_out;
    float* aw   = xout + (size_t)BB * NN * DD;

    char* w = (char*)d_ws;
    float*          si   = (float*)w;                               // 8 MB
    unsigned short* yne  = (unsigned short*)(w + (8u  << 20));      // 4 MB
    unsigned short* yT   = (unsigned short*)(w + (12u << 20));      // 4 MB
    unsigned*       pk   = (unsigned*)(w + (16u << 20));            // 4 MB
    float*          scl  = (float*)(w + (20u << 20));               // 64 KB
    float*          pdm  = (float*)(w + (20u << 20) + (64u << 10)); // 64 KB
    unsigned short* xb   = (unsigned short*)(w + (21u << 20));      // 4 MB
    unsigned short* wsb  = (unsigned short*)(w + (25u << 20));      // 32 KB
    unsigned short* wpb  = (unsigned short*)(w + (25u << 20) + (32u << 10)); // 32 KB

    dim3 blk(256);
    kernPW<<<dim3(5136), blk, 0, stream>>>(punct, mask, node, w_self, w_punct,
                                           pk, scl, pdm, xb, wsb, wpb);
    // step 0
    kernB<<<dim3(512), blk, 0, stream>>>(xb, node, wsb, wpb, w_nw, b_nw, b_self,
                                         si, yne, yT, aw);
    kernC<<<dim3(512), blk, 0, stream>>>(pk, scl, pdm, yT, si, yne, xout, xb);
    // step 1
    kernB<<<dim3(512), blk, 0, stream>>>(xb, xout, wsb, wpb, w_nw, b_nw, b_self,
                                         si, yne, yT, aw + NN);
    kernC<<<dim3(512), blk, 0, stream>>>(pk, scl, pdm, yT, si, yne, xout, xb);
}